// Round 8
// baseline (242.319 us; speedup 1.0000x reference)
//
#include <hip/hip_runtime.h>
#include <math.h>

// ---------------------------------------------------------------------------
// GCNEncoder: 3 stacked GCNConv layers (symmetric norm, self-loops) + ReLU.
//   R8: transforms rebuilt register-only (NO LDS): R7 analysis showed
//       ds_read_b128 throughput (12cy) made LDS the 3.5x bottleneck.
//       New scheme: wave = 8 output cols (wave-uniform -> W via s_load into
//       SGPRs), lane = row (X via per-lane global float4, L1-reused 4x),
//       FMA with SGPR operand. Three pipes (SMEM/VMEM/VALU), no barriers.
//   Carried: XCD-partitioned hist/fill, custom k_zero, low-VGPR 8-wide-batch
//   aggregates, W3 fused into agg2 via shuffle reduce.
// ---------------------------------------------------------------------------

#define FULL_GRID 2048
#define PARTS 8

__global__ __launch_bounds__(256) void k_zero(int* __restrict__ p, int n4) {
  int i = blockIdx.x * blockDim.x + threadIdx.x;
  const int stride = gridDim.x * blockDim.x;
  int4* p4 = (int4*)p;
  for (; i < n4; i += stride) p4[i] = make_int4(0, 0, 0, 0);
}

__global__ __launch_bounds__(256) void k_detect(const unsigned int* __restrict__ words,
                                                int* __restrict__ flag) {
  __shared__ int sm[256];
  int cnt = 0;
  #pragma unroll
  for (int j = 0; j < 8; ++j) {
    int idx = (threadIdx.x * 8 + j) * 2 + 1;  // odd words of first 4096 words
    cnt += (words[idx] == 0u) ? 1 : 0;
  }
  sm[threadIdx.x] = cnt;
  __syncthreads();
  for (int off = 128; off > 0; off >>= 1) {
    if (threadIdx.x < off) sm[threadIdx.x] += sm[threadIdx.x + off];
    __syncthreads();
  }
  if (threadIdx.x == 0) flag[0] = (sm[0] > 1024) ? 1 : 0;
}

// XCD-partitioned histogram: partition p = blockIdx&7 handles dst range
// [lo,hi) so atomics on counts stay in one XCD's L2.
__global__ __launch_bounds__(256) void k_hist(const void* __restrict__ eraw, int E,
                                              int N, const int* __restrict__ flag,
                                              int* __restrict__ counts) {
  const int is64 = flag[0];
  const int part = blockIdx.x & (PARTS - 1);
  const int lo = (int)((long long)N * part / PARTS);
  const int hi = (int)((long long)N * (part + 1) / PARTS);
  int i = (blockIdx.x >> 3) * blockDim.x + threadIdx.x;
  const int stride = (gridDim.x >> 3) * blockDim.x;
  if (is64) {
    const long long* e = (const long long*)eraw;
    for (; i < E; i += stride) {
      const int d = (int)e[(long long)E + i];
      if (d >= lo && d < hi) atomicAdd(&counts[d], 1);
    }
  } else {
    const int* e = (const int*)eraw;
    for (; i < E; i += stride) {
      const int d = e[E + i];
      if (d >= lo && d < hi) atomicAdd(&counts[d], 1);
    }
  }
}

__global__ __launch_bounds__(1024) void k_scan1(const int* __restrict__ counts,
                                                int* __restrict__ scanned,
                                                int* __restrict__ partials, int n) {
  __shared__ int sm[1024];
  const int i = blockIdx.x * 1024 + threadIdx.x;
  const int v = (i < n) ? counts[i] : 0;
  sm[threadIdx.x] = v;
  __syncthreads();
  for (int off = 1; off < 1024; off <<= 1) {
    int t = sm[threadIdx.x];
    int u = (threadIdx.x >= off) ? sm[threadIdx.x - off] : 0;
    __syncthreads();
    sm[threadIdx.x] = t + u;
    __syncthreads();
  }
  const int inc = sm[threadIdx.x];
  if (i < n) scanned[i] = inc - v;  // exclusive
  if (threadIdx.x == 1023) partials[blockIdx.x] = inc;
}

__global__ __launch_bounds__(1024) void k_scan2(int* __restrict__ partials, int nb) {
  __shared__ int sm[1024];
  const int v = (threadIdx.x < nb) ? partials[threadIdx.x] : 0;
  sm[threadIdx.x] = v;
  __syncthreads();
  for (int off = 1; off < 1024; off <<= 1) {
    int t = sm[threadIdx.x];
    int u = (threadIdx.x >= off) ? sm[threadIdx.x - off] : 0;
    __syncthreads();
    sm[threadIdx.x] = t + u;
    __syncthreads();
  }
  if (threadIdx.x < nb) partials[threadIdx.x] = sm[threadIdx.x] - v;  // exclusive
}

__global__ __launch_bounds__(256) void k_scan3(const int* __restrict__ scanned,
                                               const int* __restrict__ partials,
                                               const int* __restrict__ counts,
                                               int* __restrict__ offsets,
                                               int* __restrict__ cursor,
                                               float* __restrict__ dinv, int n) {
  int i = blockIdx.x * blockDim.x + threadIdx.x;
  const int stride = gridDim.x * blockDim.x;
  for (; i < n; i += stride) {
    const int o = scanned[i] + partials[i >> 10];
    offsets[i] = o;
    cursor[i] = o;
    dinv[i] = rsqrtf((float)counts[i] + 1.0f);  // +1 self-loop
  }
}

// XCD-partitioned fill: stores to elist confined to this partition's slice.
__global__ __launch_bounds__(256) void k_fill(const void* __restrict__ eraw, int E,
                                              int N, const int* __restrict__ flag,
                                              int* __restrict__ cursor,
                                              int* __restrict__ elist) {
  const int is64 = flag[0];
  const int part = blockIdx.x & (PARTS - 1);
  const int lo = (int)((long long)N * part / PARTS);
  const int hi = (int)((long long)N * (part + 1) / PARTS);
  int i = (blockIdx.x >> 3) * blockDim.x + threadIdx.x;
  const int stride = (gridDim.x >> 3) * blockDim.x;
  if (is64) {
    const long long* e = (const long long*)eraw;
    for (; i < E; i += stride) {
      const int d = (int)e[(long long)E + i];
      if (d >= lo && d < hi) {
        const int s = (int)e[i];
        elist[atomicAdd(&cursor[d], 1)] = s;
      }
    }
  } else {
    const int* e = (const int*)eraw;
    for (; i < E; i += stride) {
      const int d = e[E + i];
      if (d >= lo && d < hi) {
        const int s = e[i];
        elist[atomicAdd(&cursor[d], 1)] = s;
      }
    }
  }
}

__device__ __forceinline__ float f4get(const float4& v, int j) {
  return j == 0 ? v.x : (j == 1 ? v.y : (j == 2 ? v.z : v.w));
}

// hs = dinv .* (X @ W), register-only (no LDS, no barriers).
// wave = one column-group of TN cols (wave-uniform -> W via scalar loads),
// lane = row; TM row-groups of 64; X read as per-lane float4 (L1 reuse x4).
template <int F_IN, int F_OUT, int TM, int TN>
__global__ __launch_bounds__((F_OUT / TN) * 64) void k_transform_reg(
    const float* __restrict__ X, const float* __restrict__ W,
    const float* __restrict__ dinv, float* __restrict__ H, int n) {
  constexpr int K4 = F_IN / 4;
  constexpr int TN4 = TN / 4;
  constexpr int ROWS = TM * 64;

  const int lane = threadIdx.x & 63;
  const int cg = __builtin_amdgcn_readfirstlane(threadIdx.x >> 6);  // col-group
  const long long base = (long long)blockIdx.x * ROWS;
  const float4* __restrict__ X4 = (const float4*)X;
  const float* __restrict__ Wc = W + cg * TN;  // wave-uniform column slice

  long long row[TM];
  bool ok[TM];
  #pragma unroll
  for (int g = 0; g < TM; ++g) {
    row[g] = base + g * 64 + lane;
    ok[g] = row[g] < n;
  }

  float4 acc[TM][TN4];
  #pragma unroll
  for (int g = 0; g < TM; ++g)
    #pragma unroll
    for (int c = 0; c < TN4; ++c) acc[g][c] = make_float4(0.f, 0.f, 0.f, 0.f);

  float4 xcur[TM];
  #pragma unroll
  for (int g = 0; g < TM; ++g)
    xcur[g] = ok[g] ? X4[row[g] * K4] : make_float4(0.f, 0.f, 0.f, 0.f);

  #pragma unroll 4
  for (int k4 = 0; k4 < K4; ++k4) {
    float4 xnxt[TM];
    if (k4 + 1 < K4) {  // prefetch next k4 window (same L1 line 3 of 4 times)
      #pragma unroll
      for (int g = 0; g < TM; ++g)
        xnxt[g] = ok[g] ? X4[row[g] * K4 + k4 + 1] : make_float4(0.f, 0.f, 0.f, 0.f);
    }
    // wave-uniform W block for this k4: TN cols x 4 k -> SGPRs via s_load
    float w[4][TN];
    #pragma unroll
    for (int kk = 0; kk < 4; ++kk)
      #pragma unroll
      for (int c = 0; c < TN; ++c) w[kk][c] = Wc[(k4 * 4 + kk) * F_OUT + c];

    #pragma unroll
    for (int g = 0; g < TM; ++g) {
      #pragma unroll
      for (int kk = 0; kk < 4; ++kk) {
        const float xs = f4get(xcur[g], kk);
        #pragma unroll
        for (int c = 0; c < TN4; ++c) {
          acc[g][c].x = fmaf(xs, w[kk][c * 4 + 0], acc[g][c].x);
          acc[g][c].y = fmaf(xs, w[kk][c * 4 + 1], acc[g][c].y);
          acc[g][c].z = fmaf(xs, w[kk][c * 4 + 2], acc[g][c].z);
          acc[g][c].w = fmaf(xs, w[kk][c * 4 + 3], acc[g][c].w);
        }
      }
    }
    if (k4 + 1 < K4) {
      #pragma unroll
      for (int g = 0; g < TM; ++g) xcur[g] = xnxt[g];
    }
  }

  #pragma unroll
  for (int g = 0; g < TM; ++g) {
    if (ok[g]) {
      const float di = dinv[row[g]];
      #pragma unroll
      for (int c = 0; c < TN4; ++c) {
        float4 v = acc[g][c];
        v.x *= di; v.y *= di; v.z *= di; v.w *= di;
        *(float4*)&H[row[g] * F_OUT + cg * TN + c * 4] = v;
      }
    }
  }
}

// out[d][f] = relu?(b[f] + dinv[d]*(hs[d][f] + sum_s hs[s][f]))
// 8-wide predicated gather batches: 8 independent loads in flight per group.
// FUSE_W3: additionally hs3 = dinv .* (relu(out2) @ W3)  (F_OUT=2).
template <int F, bool RELU_OUT, bool FUSE_W3>
__global__ __launch_bounds__(256) void k_aggregate(const float* __restrict__ HS,
                                                   const float* __restrict__ dinv,
                                                   const int* __restrict__ offsets,
                                                   const int* __restrict__ counts,
                                                   const int* __restrict__ elist,
                                                   const float* __restrict__ bias,
                                                   const float* __restrict__ W3,
                                                   float* __restrict__ out, int n) {
  const int f = threadIdx.x % F;
  const int grp = threadIdx.x / F;
  constexpr int GRPS = 256 / F;
  const float bf = bias[f];
  float w30 = 0.f, w31 = 0.f;
  if (FUSE_W3) { w30 = W3[f * 2 + 0]; w31 = W3[f * 2 + 1]; }

  for (long long d = (long long)blockIdx.x * GRPS + grp; d < n;
       d += (long long)gridDim.x * GRPS) {
    const float di = dinv[d];
    float acc = HS[d * F + f];  // self-loop (already dinv[d]-scaled)
    const int start = offsets[d];
    const int cnt = counts[d];
    for (int j = 0; j < cnt; j += 8) {
      int idx[8];
      float v[8];
      #pragma unroll
      for (int t = 0; t < 8; ++t) {
        const int jj = (j + t < cnt) ? (j + t) : j;  // clamp to a valid slot
        idx[t] = elist[start + jj];
      }
      #pragma unroll
      for (int t = 0; t < 8; ++t) v[t] = HS[(long long)idx[t] * F + f];
      #pragma unroll
      for (int t = 0; t < 8; ++t) acc += (j + t < cnt) ? v[t] : 0.f;
    }

    float r = fmaf(di, acc, bf);
    if (RELU_OUT) r = fmaxf(r, 0.f);
    if (!FUSE_W3) {
      out[d * F + f] = r;
    } else {
      float t0 = r * w30, t1 = r * w31;
      #pragma unroll
      for (int m = 1; m < 32; m <<= 1) {
        t0 += __shfl_xor(t0, m, 64);
        t1 += __shfl_xor(t1, m, 64);
      }
      if (f == 0) {
        out[d * 2 + 0] = di * t0;
        out[d * 2 + 1] = di * t1;
      }
    }
  }
}

extern "C" void kernel_launch(void* const* d_in, const int* in_sizes, int n_in,
                              void* d_out, int out_size, void* d_ws, size_t ws_size,
                              hipStream_t stream) {
  const float* x = (const float*)d_in[0];
  const void* eraw = d_in[1];
  const float* W1 = (const float*)d_in[2];
  const float* b1 = (const float*)d_in[3];
  const float* W2 = (const float*)d_in[4];
  const float* b2 = (const float*)d_in[5];
  const float* W3 = (const float*)d_in[6];
  const float* b3 = (const float*)d_in[7];
  float* out = (float*)d_out;

  const int N = in_sizes[0] / 128;  // 100000
  const int E = in_sizes[1] / 2;    // 600000

  char* ws = (char*)d_ws;
  size_t off = 0;
  auto alloc = [&](size_t bytes) -> char* {
    char* p = ws + off;
    off = (off + bytes + 255) & ~(size_t)255;
    return p;
  };
  int*   flag     = (int*)alloc(256);
  int*   counts   = (int*)alloc((size_t)N * 4 + 16);
  int*   scanned  = (int*)alloc((size_t)N * 4);
  int*   partials = (int*)alloc(1024 * 4);
  int*   offsets  = (int*)alloc((size_t)N * 4);
  int*   cursor   = (int*)alloc((size_t)N * 4);
  int*   elist    = (int*)alloc((size_t)E * 4);
  float* dinv     = (float*)alloc((size_t)N * 4);
  float* hbuf     = (float*)alloc((size_t)N * 64 * 4);  // hs1 [N,64]; later hs3 [N,2]
  float* obuf     = (float*)alloc((size_t)N * 64 * 4);  // out1 [N,64]
  float* h2buf    = (float*)alloc((size_t)N * 32 * 4);  // hs2 [N,32]
  (void)ws_size; (void)n_in; (void)out_size;

  // ---- CSR build ----
  k_zero<<<128, 256, 0, stream>>>(counts, (N + 3) / 4);
  k_detect<<<1, 256, 0, stream>>>((const unsigned int*)eraw, flag);
  k_hist<<<FULL_GRID, 256, 0, stream>>>(eraw, E, N, flag, counts);
  const int NB = (N + 1023) >> 10;
  k_scan1<<<NB, 1024, 0, stream>>>(counts, scanned, partials, N);
  k_scan2<<<1, 1024, 0, stream>>>(partials, NB);
  k_scan3<<<(N + 255) / 256, 256, 0, stream>>>(scanned, partials, counts, offsets,
                                               cursor, dinv, N);
  k_fill<<<FULL_GRID, 256, 0, stream>>>(eraw, E, N, flag, cursor, elist);

  // ---- layer 1: hs1 = dinv.*(x@W1); out1 = relu(agg(hs1)) ----
  k_transform_reg<128, 64, 4, 8><<<(N + 255) / 256, 512, 0, stream>>>(
      x, W1, dinv, hbuf, N);
  k_aggregate<64, true, false><<<(N + 3) / 4, 256, 0, stream>>>(
      hbuf, dinv, offsets, counts, elist, b1, nullptr, obuf, N);

  // ---- layer 2: hs2 = dinv.*(out1@W2); agg + ReLU + fused W3 -> hs3 ----
  k_transform_reg<64, 32, 4, 8><<<(N + 255) / 256, 256, 0, stream>>>(
      obuf, W2, dinv, h2buf, N);
  k_aggregate<32, true, true><<<(N + 7) / 8, 256, 0, stream>>>(
      h2buf, dinv, offsets, counts, elist, b2, W3, hbuf, N);

  // ---- layer 3: agg hs3 + ReLU -> out ----
  k_aggregate<2, true, false><<<(N + 127) / 128, 256, 0, stream>>>(
      hbuf, dinv, offsets, counts, elist, b3, nullptr, out, N);
}

// Round 9
// 194.164 us; speedup vs baseline: 1.2480x; 1.2480x over previous
//
#include <hip/hip_runtime.h>
#include <math.h>

// ---------------------------------------------------------------------------
// GCNEncoder: 3 stacked GCNConv layers (symmetric norm, self-loops) + ReLU.
//   R9: (a) transforms reverted to R5 LDS-tiled GEMM (R8 reg-only was 2x
//       slower: uncoalesced 512B-stride X loads, W never scalarized);
//       (b) aggregates rebuilt edge-group-parallel: LPE=F/4 lanes x float4
//       per edge -> 4-8 edges per wave-instruction, 2 batches in flight,
//       shfl_xor cross-group reduce (shortens idx->gather chains 4-8x);
//       (c) detect merged into zero, scan2 merged into scan3 (10 launches).
//   Carried: XCD-partitioned hist/fill, XOR-swizzled X staging, W dbuf.
// ---------------------------------------------------------------------------

#define FULL_GRID 2048
#define PARTS 8

typedef const __attribute__((address_space(1))) void* gas_ptr;
typedef __attribute__((address_space(3))) void* las_ptr;

__device__ __forceinline__ void gld16(const void* g, void* l) {
  __builtin_amdgcn_global_load_lds((gas_ptr)g, (las_ptr)l, 16, 0, 0);
}

// blocks 0..n-1: zero counts; last block: edge dtype detect.
__global__ __launch_bounds__(256) void k_init(int* __restrict__ p, int n4,
                                              const unsigned int* __restrict__ words,
                                              int* __restrict__ flag) {
  if (blockIdx.x == gridDim.x - 1) {
    __shared__ int sm[256];
    int cnt = 0;
    #pragma unroll
    for (int j = 0; j < 8; ++j) {
      int idx = (threadIdx.x * 8 + j) * 2 + 1;  // odd words of first 4096 words
      cnt += (words[idx] == 0u) ? 1 : 0;
    }
    sm[threadIdx.x] = cnt;
    __syncthreads();
    for (int off = 128; off > 0; off >>= 1) {
      if (threadIdx.x < off) sm[threadIdx.x] += sm[threadIdx.x + off];
      __syncthreads();
    }
    if (threadIdx.x == 0) flag[0] = (sm[0] > 1024) ? 1 : 0;
    return;
  }
  int i = blockIdx.x * blockDim.x + threadIdx.x;
  const int stride = (gridDim.x - 1) * blockDim.x;
  int4* p4 = (int4*)p;
  for (; i < n4; i += stride) p4[i] = make_int4(0, 0, 0, 0);
}

// XCD-partitioned histogram: partition p = blockIdx&7 handles dst range
// [lo,hi) so atomics on counts stay in one XCD's L2.
__global__ __launch_bounds__(256) void k_hist(const void* __restrict__ eraw, int E,
                                              int N, const int* __restrict__ flag,
                                              int* __restrict__ counts) {
  const int is64 = flag[0];
  const int part = blockIdx.x & (PARTS - 1);
  const int lo = (int)((long long)N * part / PARTS);
  const int hi = (int)((long long)N * (part + 1) / PARTS);
  int i = (blockIdx.x >> 3) * blockDim.x + threadIdx.x;
  const int stride = (gridDim.x >> 3) * blockDim.x;
  if (is64) {
    const long long* e = (const long long*)eraw;
    for (; i < E; i += stride) {
      const int d = (int)e[(long long)E + i];
      if (d >= lo && d < hi) atomicAdd(&counts[d], 1);
    }
  } else {
    const int* e = (const int*)eraw;
    for (; i < E; i += stride) {
      const int d = e[E + i];
      if (d >= lo && d < hi) atomicAdd(&counts[d], 1);
    }
  }
}

__global__ __launch_bounds__(1024) void k_scan1(const int* __restrict__ counts,
                                                int* __restrict__ scanned,
                                                int* __restrict__ partials, int n) {
  __shared__ int sm[1024];
  const int i = blockIdx.x * 1024 + threadIdx.x;
  const int v = (i < n) ? counts[i] : 0;
  sm[threadIdx.x] = v;
  __syncthreads();
  for (int off = 1; off < 1024; off <<= 1) {
    int t = sm[threadIdx.x];
    int u = (threadIdx.x >= off) ? sm[threadIdx.x - off] : 0;
    __syncthreads();
    sm[threadIdx.x] = t + u;
    __syncthreads();
  }
  const int inc = sm[threadIdx.x];
  if (i < n) scanned[i] = inc - v;  // exclusive within block
  if (threadIdx.x == 1023) partials[blockIdx.x] = inc;  // block total
}

// scan of partials folded in: each block scans partials[] in LDS (NB <= 1024).
__global__ __launch_bounds__(256) void k_scan3(const int* __restrict__ scanned,
                                               const int* __restrict__ partials,
                                               int nb,
                                               const int* __restrict__ counts,
                                               int* __restrict__ offsets,
                                               int* __restrict__ cursor,
                                               float* __restrict__ dinv, int n) {
  __shared__ int ps[1024];
  for (int t = threadIdx.x; t < nb; t += 256) ps[t] = partials[t];
  __syncthreads();
  if (threadIdx.x == 0) {  // serial exclusive scan of <=1024 block totals
    int run = 0;
    for (int b = 0; b < nb; ++b) { const int v = ps[b]; ps[b] = run; run += v; }
  }
  __syncthreads();
  int i = blockIdx.x * blockDim.x + threadIdx.x;
  const int stride = gridDim.x * blockDim.x;
  for (; i < n; i += stride) {
    const int o = scanned[i] + ps[i >> 10];
    offsets[i] = o;
    cursor[i] = o;
    dinv[i] = rsqrtf((float)counts[i] + 1.0f);  // +1 self-loop
  }
}

// XCD-partitioned fill: stores to elist confined to this partition's slice.
__global__ __launch_bounds__(256) void k_fill(const void* __restrict__ eraw, int E,
                                              int N, const int* __restrict__ flag,
                                              int* __restrict__ cursor,
                                              int* __restrict__ elist) {
  const int is64 = flag[0];
  const int part = blockIdx.x & (PARTS - 1);
  const int lo = (int)((long long)N * part / PARTS);
  const int hi = (int)((long long)N * (part + 1) / PARTS);
  int i = (blockIdx.x >> 3) * blockDim.x + threadIdx.x;
  const int stride = (gridDim.x >> 3) * blockDim.x;
  if (is64) {
    const long long* e = (const long long*)eraw;
    for (; i < E; i += stride) {
      const int d = (int)e[(long long)E + i];
      if (d >= lo && d < hi) {
        const int s = (int)e[i];
        elist[atomicAdd(&cursor[d], 1)] = s;
      }
    }
  } else {
    const int* e = (const int*)eraw;
    for (; i < E; i += stride) {
      const int d = e[E + i];
      if (d >= lo && d < hi) {
        const int s = e[i];
        elist[atomicAdd(&cursor[d], 1)] = s;
      }
    }
  }
}

// hs = dinv .* (X @ W).  256 thr, TMx4 thread tile (R5-proven).
// X tile XOR-swizzled: LDS float4-slot row*K4+c holds X[row][4*(c^(row&7))..].
// Staged via global_load_lds with PRE-SWIZZLED global source (linear LDS dest).
// W chunks double-buffered (single-buffered when NKC==1).
template <int F_IN, int F_OUT, int TILE_M, int KC>
__global__ __launch_bounds__(256) void k_transform(const float* __restrict__ X,
                                                   const float* __restrict__ W,
                                                   const float* __restrict__ dinv,
                                                   float* __restrict__ H, int n) {
  constexpr int COLT = F_OUT / 4;
  constexpr int ROWT = 256 / COLT;
  constexpr int TM = TILE_M / ROWT;
  constexpr int NKC = F_IN / KC;
  constexpr int K4 = F_IN / 4;
  constexpr int NWB = (NKC > 1) ? 2 : 1;  // W buffers
  static_assert(TM * ROWT == TILE_M && COLT * 4 == F_OUT, "tiling");
  static_assert((TILE_M * F_IN * 4) % 1024 == 0 && (KC * F_OUT * 4) % 1024 == 0, "segs");
  static_assert(K4 >= 8, "swizzle range");
  static_assert(ROWT % 8 == 0, "swizzle invariance across r");

  __shared__ __align__(16) float Xs[TILE_M * F_IN];
  __shared__ __align__(16) float Ws[NWB][KC * F_OUT];

  const int tid = threadIdx.x;
  const int lane = tid & 63;
  const int wid = tid >> 6;
  const long long base = (long long)blockIdx.x * TILE_M;

  const float4* __restrict__ X4 = (const float4*)X;
  if (base + TILE_M <= n) {  // full tile: async staged, pre-swizzled source
    constexpr int SEGS = TILE_M * F_IN * 4 / 1024;  // 1KB segments
    constexpr int PW = SEGS / 4;
    #pragma unroll
    for (int j = 0; j < PW; ++j) {
      const int seg = wid * PW + j;
      const int slot = seg * 64 + lane;           // linear LDS float4 slot
      const int row = slot / K4;
      const int c = slot % K4;
      const int ksrc = c ^ (row & 7);             // inverse swizzle on source
      gld16(&X4[(base + row) * K4 + ksrc], &Xs[seg * 256]);
    }
  } else {  // tail tile: guarded staging with same swizzled layout
    for (int slot = tid; slot < TILE_M * K4; slot += 256) {
      const int row = slot / K4;
      const int c = slot % K4;
      float4 v = make_float4(0.f, 0.f, 0.f, 0.f);
      if (base + row < n) v = X4[(base + row) * K4 + (c ^ (row & 7))];
      ((float4*)Xs)[slot] = v;
    }
  }

  // stage W chunk 0
  constexpr int WSEG = KC * F_OUT * 4 / 1024;
  constexpr int WPW = WSEG / 4;
  {
    #pragma unroll
    for (int j = 0; j < WPW; ++j) {
      const int seg = wid * WPW + j;
      gld16(W + seg * 256 + lane * 4, &Ws[0][seg * 256]);
    }
  }

  const int ct = tid % COLT;
  const int rt = tid / COLT;
  const int sw = rt & 7;  // row&7 invariant across r (ROWT multiple of 8)

  float4 acc[TM];
  #pragma unroll
  for (int r = 0; r < TM; ++r) acc[r] = make_float4(0.f, 0.f, 0.f, 0.f);

  const float4* Xs4 = (const float4*)Xs;

  for (int kc = 0; kc < NKC; ++kc) {
    __syncthreads();  // current W chunk + X staged (barrier drains vmcnt)
    if (NKC > 1 && kc + 1 < NKC) {  // prefetch next W chunk into other buffer
      const float* wb = W + (kc + 1) * KC * F_OUT;
      #pragma unroll
      for (int j = 0; j < WPW; ++j) {
        const int seg = wid * WPW + j;
        gld16(wb + seg * 256 + lane * 4, &Ws[(kc + 1) & (NWB - 1)][seg * 256]);
      }
    }
    const float4* Ws4 = (const float4*)Ws[kc & (NWB - 1)];
    #pragma unroll
    for (int k4 = 0; k4 < KC / 4; ++k4) {
      const int kk = kc * (KC / 4) + k4;
      float4 wv0 = Ws4[(k4 * 4 + 0) * COLT + ct];
      float4 wv1 = Ws4[(k4 * 4 + 1) * COLT + ct];
      float4 wv2 = Ws4[(k4 * 4 + 2) * COLT + ct];
      float4 wv3 = Ws4[(k4 * 4 + 3) * COLT + ct];
      #pragma unroll
      for (int r = 0; r < TM; ++r) {
        const float4 xv = Xs4[(rt + r * ROWT) * K4 + (kk ^ sw)];
        acc[r].x = fmaf(xv.x, wv0.x, acc[r].x);
        acc[r].y = fmaf(xv.x, wv0.y, acc[r].y);
        acc[r].z = fmaf(xv.x, wv0.z, acc[r].z);
        acc[r].w = fmaf(xv.x, wv0.w, acc[r].w);
        acc[r].x = fmaf(xv.y, wv1.x, acc[r].x);
        acc[r].y = fmaf(xv.y, wv1.y, acc[r].y);
        acc[r].z = fmaf(xv.y, wv1.z, acc[r].z);
        acc[r].w = fmaf(xv.y, wv1.w, acc[r].w);
        acc[r].x = fmaf(xv.z, wv2.x, acc[r].x);
        acc[r].y = fmaf(xv.z, wv2.y, acc[r].y);
        acc[r].z = fmaf(xv.z, wv2.z, acc[r].z);
        acc[r].w = fmaf(xv.z, wv2.w, acc[r].w);
        acc[r].x = fmaf(xv.w, wv3.x, acc[r].x);
        acc[r].y = fmaf(xv.w, wv3.y, acc[r].y);
        acc[r].z = fmaf(xv.w, wv3.z, acc[r].z);
        acc[r].w = fmaf(xv.w, wv3.w, acc[r].w);
      }
    }
  }

  #pragma unroll
  for (int r = 0; r < TM; ++r) {
    const long long row = base + rt + r * ROWT;
    if (row < n) {
      const float di = dinv[row];
      float4 v = acc[r];
      v.x *= di; v.y *= di; v.z *= di; v.w *= di;
      *(float4*)&H[row * F_OUT + ct * 4] = v;
    }
  }
}

// Edge-group-parallel aggregate. Wave = one dst node; LPE=F/4 lanes per edge
// (float4 feature slice), EPW=64/LPE edges per wave-instruction, 2 batches in
// flight. Cross-edge-group reduce via shfl_xor.
// out[d][:] = relu?(b + dinv[d]*(hs[d] + sum_s hs[s]))
// FUSE_W3: instead writes hs3 = dinv .* (relu(out2) @ W3)  (2 floats).
template <int F, bool RELU_OUT, bool FUSE_W3>
__global__ __launch_bounds__(256) void k_agg_vec(const float* __restrict__ HS,
                                                 const float* __restrict__ dinv,
                                                 const int* __restrict__ offsets,
                                                 const int* __restrict__ counts,
                                                 const int* __restrict__ elist,
                                                 const float* __restrict__ bias,
                                                 const float* __restrict__ W3,
                                                 float* __restrict__ out, int n) {
  constexpr int LPE = F / 4;        // lanes per edge
  constexpr int EPW = 64 / LPE;     // edges per wave-instruction
  const int lane = threadIdx.x & 63;
  const int wv = (blockIdx.x * (blockDim.x >> 6)) + (threadIdx.x >> 6);
  const int nwaves = gridDim.x * (blockDim.x >> 6);
  const int g = lane / LPE;         // edge slot within batch
  const int fl = lane % LPE;        // feature-slice index
  const float4 bf = *(const float4*)&bias[fl * 4];

  float w3a0 = 0.f, w3a1 = 0.f, w3a2 = 0.f, w3a3 = 0.f;
  float w3b0 = 0.f, w3b1 = 0.f, w3b2 = 0.f, w3b3 = 0.f;
  if (FUSE_W3) {
    w3a0 = W3[(fl * 4 + 0) * 2 + 0]; w3b0 = W3[(fl * 4 + 0) * 2 + 1];
    w3a1 = W3[(fl * 4 + 1) * 2 + 0]; w3b1 = W3[(fl * 4 + 1) * 2 + 1];
    w3a2 = W3[(fl * 4 + 2) * 2 + 0]; w3b2 = W3[(fl * 4 + 2) * 2 + 1];
    w3a3 = W3[(fl * 4 + 3) * 2 + 0]; w3b3 = W3[(fl * 4 + 3) * 2 + 1];
  }

  for (long long d = wv; d < n; d += nwaves) {
    const float di = dinv[d];
    const int start = offsets[d];
    const int cnt = counts[d];
    float4 acc = make_float4(0.f, 0.f, 0.f, 0.f);
    if (g == 0) acc = *(const float4*)&HS[d * F + fl * 4];  // self (pre-scaled)

    for (int j = 0; j < cnt; j += 2 * EPW) {
      const int e0 = j + g;
      const int e1 = j + EPW + g;
      const int i0 = elist[start + (e0 < cnt ? e0 : cnt - 1)];
      const int i1 = elist[start + (e1 < cnt ? e1 : cnt - 1)];
      const float4 v0 = *(const float4*)&HS[(long long)i0 * F + fl * 4];
      const float4 v1 = *(const float4*)&HS[(long long)i1 * F + fl * 4];
      if (e0 < cnt) {
        acc.x += v0.x; acc.y += v0.y; acc.z += v0.z; acc.w += v0.w;
      }
      if (e1 < cnt) {
        acc.x += v1.x; acc.y += v1.y; acc.z += v1.z; acc.w += v1.w;
      }
    }
    // reduce across edge groups (lanes differing in bits >= log2(LPE))
    #pragma unroll
    for (int m = LPE; m < 64; m <<= 1) {
      acc.x += __shfl_xor(acc.x, m, 64);
      acc.y += __shfl_xor(acc.y, m, 64);
      acc.z += __shfl_xor(acc.z, m, 64);
      acc.w += __shfl_xor(acc.w, m, 64);
    }
    float4 r;
    r.x = fmaf(di, acc.x, bf.x);
    r.y = fmaf(di, acc.y, bf.y);
    r.z = fmaf(di, acc.z, bf.z);
    r.w = fmaf(di, acc.w, bf.w);
    if (RELU_OUT) {
      r.x = fmaxf(r.x, 0.f); r.y = fmaxf(r.y, 0.f);
      r.z = fmaxf(r.z, 0.f); r.w = fmaxf(r.w, 0.f);
    }
    if (!FUSE_W3) {
      if (g == 0) *(float4*)&out[d * F + fl * 4] = r;
    } else {
      float t0 = r.x * w3a0 + r.y * w3a1 + r.z * w3a2 + r.w * w3a3;
      float t1 = r.x * w3b0 + r.y * w3b1 + r.z * w3b2 + r.w * w3b3;
      #pragma unroll
      for (int m = 1; m < LPE; m <<= 1) {
        t0 += __shfl_xor(t0, m, 64);
        t1 += __shfl_xor(t1, m, 64);
      }
      if (lane == 0) {
        out[d * 2 + 0] = di * t0;
        out[d * 2 + 1] = di * t1;
      }
    }
  }
}

// scalar aggregate for tiny F (layer 3, F=2)
template <int F, bool RELU_OUT>
__global__ __launch_bounds__(256) void k_aggregate(const float* __restrict__ HS,
                                                   const float* __restrict__ dinv,
                                                   const int* __restrict__ offsets,
                                                   const int* __restrict__ counts,
                                                   const int* __restrict__ elist,
                                                   const float* __restrict__ bias,
                                                   float* __restrict__ out, int n) {
  const int f = threadIdx.x % F;
  const int grp = threadIdx.x / F;
  constexpr int GRPS = 256 / F;
  const float bf = bias[f];

  for (long long d = (long long)blockIdx.x * GRPS + grp; d < n;
       d += (long long)gridDim.x * GRPS) {
    const float di = dinv[d];
    float acc = HS[d * F + f];  // self-loop (already dinv[d]-scaled)
    const int start = offsets[d];
    const int cnt = counts[d];
    for (int j = 0; j < cnt; j += 8) {
      int idx[8];
      float v[8];
      #pragma unroll
      for (int t = 0; t < 8; ++t) {
        const int jj = (j + t < cnt) ? (j + t) : j;
        idx[t] = elist[start + jj];
      }
      #pragma unroll
      for (int t = 0; t < 8; ++t) v[t] = HS[(long long)idx[t] * F + f];
      #pragma unroll
      for (int t = 0; t < 8; ++t) acc += (j + t < cnt) ? v[t] : 0.f;
    }
    float r = fmaf(di, acc, bf);
    if (RELU_OUT) r = fmaxf(r, 0.f);
    out[d * F + f] = r;
  }
}

extern "C" void kernel_launch(void* const* d_in, const int* in_sizes, int n_in,
                              void* d_out, int out_size, void* d_ws, size_t ws_size,
                              hipStream_t stream) {
  const float* x = (const float*)d_in[0];
  const void* eraw = d_in[1];
  const float* W1 = (const float*)d_in[2];
  const float* b1 = (const float*)d_in[3];
  const float* W2 = (const float*)d_in[4];
  const float* b2 = (const float*)d_in[5];
  const float* W3 = (const float*)d_in[6];
  const float* b3 = (const float*)d_in[7];
  float* out = (float*)d_out;

  const int N = in_sizes[0] / 128;  // 100000
  const int E = in_sizes[1] / 2;    // 600000

  char* ws = (char*)d_ws;
  size_t off = 0;
  auto alloc = [&](size_t bytes) -> char* {
    char* p = ws + off;
    off = (off + bytes + 255) & ~(size_t)255;
    return p;
  };
  int*   flag     = (int*)alloc(256);
  int*   counts   = (int*)alloc((size_t)N * 4 + 16);
  int*   scanned  = (int*)alloc((size_t)N * 4);
  int*   partials = (int*)alloc(1024 * 4);
  int*   offsets  = (int*)alloc((size_t)N * 4);
  int*   cursor   = (int*)alloc((size_t)N * 4);
  int*   elist    = (int*)alloc((size_t)E * 4);
  float* dinv     = (float*)alloc((size_t)N * 4);
  float* hbuf     = (float*)alloc((size_t)N * 64 * 4);  // hs1 [N,64]; later hs3 [N,2]
  float* obuf     = (float*)alloc((size_t)N * 64 * 4);  // out1 [N,64]
  float* h2buf    = (float*)alloc((size_t)N * 32 * 4);  // hs2 [N,32]
  (void)ws_size; (void)n_in; (void)out_size;

  // ---- CSR build ----
  k_init<<<129, 256, 0, stream>>>(counts, (N + 3) / 4, (const unsigned int*)eraw,
                                  flag);
  k_hist<<<FULL_GRID, 256, 0, stream>>>(eraw, E, N, flag, counts);
  const int NB = (N + 1023) >> 10;
  k_scan1<<<NB, 1024, 0, stream>>>(counts, scanned, partials, N);
  k_scan3<<<(N + 255) / 256, 256, 0, stream>>>(scanned, partials, NB, counts,
                                               offsets, cursor, dinv, N);
  k_fill<<<FULL_GRID, 256, 0, stream>>>(eraw, E, N, flag, cursor, elist);

  // ---- layer 1: hs1 = dinv.*(x@W1); out1 = relu(agg(hs1)) ----
  k_transform<128, 64, 64, 16><<<(N + 63) / 64, 256, 0, stream>>>(x, W1, dinv, hbuf, N);
  k_agg_vec<64, true, false><<<FULL_GRID, 256, 0, stream>>>(
      hbuf, dinv, offsets, counts, elist, b1, nullptr, obuf, N);

  // ---- layer 2: hs2 = dinv.*(out1@W2); agg + ReLU + fused W3 -> hs3 ----
  k_transform<64, 32, 128, 64><<<(N + 127) / 128, 256, 0, stream>>>(obuf, W2, dinv,
                                                                    h2buf, N);
  k_agg_vec<32, true, true><<<FULL_GRID, 256, 0, stream>>>(
      h2buf, dinv, offsets, counts, elist, b2, W3, hbuf, N);

  // ---- layer 3: agg hs3 + ReLU -> out ----
  k_aggregate<2, true><<<(N + 127) / 128, 256, 0, stream>>>(
      hbuf, dinv, offsets, counts, elist, b3, out, N);
}